// Round 2
// baseline (4146.001 us; speedup 1.0000x reference)
//
#include <hip/hip_runtime.h>
#include <hip/hip_fp16.h>

// RNTensorN: 11-level binary-tree RNTN, L=2048, D=256, C=5.
// Precision scheme (needed: per-level injection < ~4e-5 due to ~150x recursive
// amplification measured in round 1):
//   c = c_hi(f16) + c_lo(f16); V = V_hi(f16) + V_lo8(fp8 e4m3, scale 2^16)
//   G = c_hi@V_hi + c_lo@V_hi (f16 MFMA) + c8@V_lo8 (fp8 MFMA, x 2^-16)
//   stage-2 weights f32, linear term f32 VALU in phase B, tanh f32.

#define DD 256
#define TWO_D 512
#define MW_ 131072      // 2D*D columns of Vm
#define AT 4            // a's per block (phase A)

typedef _Float16 half_t;
typedef _Float16 half8_t __attribute__((ext_vector_type(8)));
typedef float f32x4 __attribute__((ext_vector_type(4)));
typedef long i64t;

#define MFMA16(A, B, C) __builtin_amdgcn_mfma_f32_16x16x32_f16(A, B, C, 0, 0, 0)
#define MFMA8(A, B, C) __builtin_amdgcn_mfma_f32_16x16x32_fp8_fp8(A, B, C, 0, 0, 0)

__device__ __forceinline__ void gll16(const void* g, void* l) {
  __builtin_amdgcn_global_load_lds(
      (const __attribute__((address_space(1))) unsigned int*)g,
      (__attribute__((address_space(3))) unsigned int*)l, 16, 0, 0);
}

__device__ __forceinline__ unsigned char to_fp8(float v) {
  return (unsigned char)(__builtin_amdgcn_cvt_pk_fp8_f32(v, 0.f, 0, false) & 0xff);
}

// ---- V split+transpose: V[k][m] f32 -> Vth[m][k] f16, Vtl8[m][k] fp8*2^16 --
__global__ __launch_bounds__(256) void k_split_v(
    const float* __restrict__ V, half_t* __restrict__ Vth,
    unsigned char* __restrict__ Vtl8) {
  __shared__ unsigned short lh[32][264];
  __shared__ unsigned char ll[32][264];
  const int t = threadIdx.x;
  const int m0 = blockIdx.x * 256;
  const int i0 = blockIdx.y * 32;
  #pragma unroll
  for (int r = 0; r < 32; ++r) {
    float v = V[(size_t)(i0 + r) * MW_ + m0 + t];
    half_t h = (half_t)v;
    lh[r][t] = *(unsigned short*)&h;
    ll[r][t] = to_fp8((v - (float)h) * 65536.f);
  }
  __syncthreads();
  unsigned int wb[16];
  #pragma unroll
  for (int k = 0; k < 16; ++k)
    wb[k] = (unsigned int)lh[2 * k][t] | ((unsigned int)lh[2 * k + 1][t] << 16);
  uint4* dh = (uint4*)(Vth + (size_t)(m0 + t) * TWO_D + i0);
  dh[0] = make_uint4(wb[0], wb[1], wb[2], wb[3]);
  dh[1] = make_uint4(wb[4], wb[5], wb[6], wb[7]);
  dh[2] = make_uint4(wb[8], wb[9], wb[10], wb[11]);
  dh[3] = make_uint4(wb[12], wb[13], wb[14], wb[15]);
  unsigned int b8[8];
  #pragma unroll
  for (int j = 0; j < 8; ++j)
    b8[j] = (unsigned int)ll[4 * j][t] | ((unsigned int)ll[4 * j + 1][t] << 8) |
            ((unsigned int)ll[4 * j + 2][t] << 16) |
            ((unsigned int)ll[4 * j + 3][t] << 24);
  uint4* dl = (uint4*)(Vtl8 + (size_t)(m0 + t) * TWO_D + i0);
  dl[0] = make_uint4(b8[0], b8[1], b8[2], b8[3]);
  dl[1] = make_uint4(b8[4], b8[5], b8[6], b8[7]);
}

// ---- WwT[b][a] = Ww[a][b] (f32), for the phase-B linear term ---------------
__global__ void k_prep_w(const float* __restrict__ Ww, float* __restrict__ WwT) {
  const int b = blockIdx.x, t = threadIdx.x;
  WwT[(size_t)b * DD + t] = Ww[(size_t)t * TWO_D + b];
}

// ---- leaves: gather embeddings -> reps f32 + all c-representations ---------
__global__ void k_leaves(const int* __restrict__ tok, const float* __restrict__ emb,
                         float* __restrict__ reps, half_t* __restrict__ Chh,
                         half_t* __restrict__ Chl, unsigned char* __restrict__ Ch8,
                         float* __restrict__ Ch32) {
  const int row = blockIdx.x, t = threadIdx.x;
  float v = emb[(size_t)tok[row] * DD + t];
  size_t o = (size_t)row * DD + t;
  reps[o] = v;
  half_t h = (half_t)v;
  Chh[o] = h;
  Chl[o] = (half_t)(v - (float)h);
  Ch8[o] = to_fp8(v);
  Ch32[o] = v;
}

// ---- phase A: split-precision fused bilinear GEMM --------------------------
// grid (64*bn, 8): bxa = x&63 (a-tile), nch = x>>6 (node chunk of 128), bz=y.
// 8 waves: kh = wv>>2 (k-half of 256), wq = wv&3 (node quad: 2 groups of 16).
__global__ __launch_bounds__(512, 2) void k_level_a(
    const half_t* __restrict__ Chh, const half_t* __restrict__ Chl,
    const unsigned char* __restrict__ Ch8, const float* __restrict__ Ch32,
    const half_t* __restrict__ Vth, const unsigned char* __restrict__ Vtl8,
    float* __restrict__ part, int n) {
  extern __shared__ char smem[];
  char* R0 = smem;            // 64 KB: V_hi tile, 64 rows x 1024 B
  char* R1 = smem + 65536;    // 32 KB: V_lo8 tile, 64 rows x 512 B
  const int tid = threadIdx.x;
  const int lane = tid & 63;
  const int wv = tid >> 6;
  const int l15 = lane & 15;
  const int l4 = lane >> 4;
  const int kh = wv >> 2;
  const int wq = wv & 3;
  const int bxa = blockIdx.x & 63;
  const int nch = blockIdx.x >> 6;
  const int bz = blockIdx.y;
  const int nbase0 = nch * 128 + wq * 32;
  const int nbase1 = nbase0 + 16;
  const int swz = (l15 & 7) << 4;
  const int kbase = kh * 256;       // this wave's k-half (elements)
  const int a_base = bxa * AT;

  // A fragments for this wave's k-half: hi, lo (f16) and fp8, 2 node groups.
  half8_t afh0[8], afh1[8], afl0[8], afl1[8];
  i64t af80[8], af81[8];
  {
    int node0 = nbase0 + l15, node1 = nbase1 + l15;
    bool ok0 = node0 < n, ok1 = node1 < n;
    const half8_t z = {};
    const size_t o0 = (size_t)node0 * TWO_D + kbase + 8 * l4;
    const size_t o1 = (size_t)node1 * TWO_D + kbase + 8 * l4;
    #pragma unroll
    for (int kc = 0; kc < 8; ++kc) {
      half8_t a0 = *(const half8_t*)(Chh + o0 + kc * 32);
      half8_t a1 = *(const half8_t*)(Chh + o1 + kc * 32);
      half8_t b0 = *(const half8_t*)(Chl + o0 + kc * 32);
      half8_t b1 = *(const half8_t*)(Chl + o1 + kc * 32);
      i64t c0 = *(const i64t*)(Ch8 + o0 + kc * 32);
      i64t c1 = *(const i64t*)(Ch8 + o1 + kc * 32);
      afh0[kc] = ok0 ? a0 : z;   afh1[kc] = ok1 ? a1 : z;
      afl0[kc] = ok0 ? b0 : z;   afl1[kc] = ok1 ? b1 : z;
      af80[kc] = ok0 ? c0 : (i64t)0; af81[kc] = ok1 ? c1 : (i64t)0;
    }
  }

  auto stage_vhi = [&](int a) {
    const size_t mb = ((size_t)(a_base + a) * TWO_D + bz * 64) * 1024;
    #pragma unroll
    for (int j = 0; j < 8; ++j) {
      int row = wv * 8 + j;
      int so = (lane * 16) ^ ((row & 7) << 4);
      gll16((const char*)Vth + mb + (size_t)row * 1024 + so, R0 + row * 1024);
    }
  };
  auto stage_vlo = [&](int a) {
    const size_t mb = ((size_t)(a_base + a) * TWO_D + bz * 64) * 512;
    #pragma unroll
    for (int j = 0; j < 4; ++j) {
      int r0 = wv * 8 + j * 2;
      int row = r0 + (lane >> 5);
      int so = ((lane & 31) * 16) ^ ((row & 7) << 4);
      gll16((const char*)Vtl8 + mb + (size_t)row * 512 + so, R1 + r0 * 512);
    }
  };

  stage_vhi(0);

  #pragma unroll 1
  for (int a = 0; a < AT; ++a) {
    const f32x4 zz = {0.f, 0.f, 0.f, 0.f};
    f32x4 accA[4] = {zz, zz, zz, zz};
    f32x4 accB[4] = {zz, zz, zz, zz};

    __syncthreads();                      // R0 = V_hi(a) ready
    stage_vlo(a);                         // -> R1 (overlaps HI pass)

    {  // HI pass: G1 (c_hi@V_hi) + G2 (c_lo@V_hi)
      const int xb = kbase * 2;
      #pragma unroll
      for (int kc = 0; kc < 8; ++kc) {
        int xo = (xb + kc * 64 + 16 * l4) ^ swz;
        const char* bp = R0 + l15 * 1024 + xo;
        half8_t b0 = *(const half8_t*)(bp);
        half8_t b1 = *(const half8_t*)(bp + 16384);
        half8_t b2 = *(const half8_t*)(bp + 32768);
        half8_t b3 = *(const half8_t*)(bp + 49152);
        accA[0] = MFMA16(afh0[kc], b0, accA[0]);
        accA[0] = MFMA16(afl0[kc], b0, accA[0]);
        accB[0] = MFMA16(afh1[kc], b0, accB[0]);
        accB[0] = MFMA16(afl1[kc], b0, accB[0]);
        accA[1] = MFMA16(afh0[kc], b1, accA[1]);
        accA[1] = MFMA16(afl0[kc], b1, accA[1]);
        accB[1] = MFMA16(afh1[kc], b1, accB[1]);
        accB[1] = MFMA16(afl1[kc], b1, accB[1]);
        accA[2] = MFMA16(afh0[kc], b2, accA[2]);
        accA[2] = MFMA16(afl0[kc], b2, accA[2]);
        accB[2] = MFMA16(afh1[kc], b2, accB[2]);
        accB[2] = MFMA16(afl1[kc], b2, accB[2]);
        accA[3] = MFMA16(afh0[kc], b3, accA[3]);
        accA[3] = MFMA16(afl0[kc], b3, accA[3]);
        accB[3] = MFMA16(afh1[kc], b3, accB[3]);
        accB[3] = MFMA16(afl1[kc], b3, accB[3]);
      }
    }

    __syncthreads();                      // R1 ready; all waves done with R0
    if (a + 1 < AT) stage_vhi(a + 1);     // -> R0 (overlaps LO pass)

    // LO pass: G3 = c8 @ V_lo8, descale 2^-16 into f32 acc
    #pragma unroll
    for (int mt = 0; mt < 4; ++mt) {
      f32x4 p0 = zz, p1 = zz;
      #pragma unroll
      for (int kc = 0; kc < 8; ++kc) {
        int xo = (kbase + kc * 32 + 8 * l4) ^ swz;
        i64t bb = *(const i64t*)(R1 + (mt * 16 + l15) * 512 + xo);
        p0 = MFMA8(af80[kc], bb, p0);
        p1 = MFMA8(af81[kc], bb, p1);
      }
      accA[mt] += p0 * 1.52587890625e-05f;
      accB[mt] += p1 * 1.52587890625e-05f;
    }

    // stage 2: tens partial = sum_b G[n][b] * c32[n][b]
    float aS0[4] = {0.f, 0.f, 0.f, 0.f};
    float aS1[4] = {0.f, 0.f, 0.f, 0.f};
    {
      int bc = bz * 64 + l15;
      #pragma unroll
      for (int mt = 0; mt < 4; ++mt) {
        #pragma unroll
        for (int r = 0; r < 4; ++r) {
          int rr = 4 * l4 + r;
          float w0 = Ch32[(size_t)(nbase0 + rr) * TWO_D + bc + mt * 16];
          float w1 = Ch32[(size_t)(nbase1 + rr) * TWO_D + bc + mt * 16];
          aS0[r] += w0 * accA[mt][r];
          aS1[r] += w1 * accB[mt][r];
        }
      }
    }
    #pragma unroll
    for (int r = 0; r < 4; ++r) {
      float v0 = aS0[r], v1 = aS1[r];
      v0 += __shfl_xor(v0, 1); v0 += __shfl_xor(v0, 2);
      v0 += __shfl_xor(v0, 4); v0 += __shfl_xor(v0, 8);
      v1 += __shfl_xor(v1, 1); v1 += __shfl_xor(v1, 2);
      v1 += __shfl_xor(v1, 4); v1 += __shfl_xor(v1, 8);
      aS0[r] = v0; aS1[r] = v1;
    }
    if (l15 < 4) {
      int a_glob = a_base + a;
      float o0 = (l15 == 0) ? aS0[0] : (l15 == 1) ? aS0[1] : (l15 == 2) ? aS0[2] : aS0[3];
      float o1 = (l15 == 0) ? aS1[0] : (l15 == 1) ? aS1[1] : (l15 == 2) ? aS1[2] : aS1[3];
      int n0 = nbase0 + 4 * l4 + l15;
      int n1 = nbase1 + 4 * l4 + l15;
      size_t sl = (size_t)(bz * 2 + kh) * 1024;
      if (n0 < n) part[(sl + n0) * DD + a_glob] = o0;
      if (n1 < n) part[(sl + n1) * DD + a_glob] = o1;
    }
  }
}

// ---- phase B: sum 16 partial slices + f32 linear term + bias + tanh --------
__global__ __launch_bounds__(256) void k_level_b(
    const float* __restrict__ part, const float* __restrict__ WwT,
    const float* __restrict__ Wb, const float* __restrict__ Cin32,
    float* __restrict__ reps_out, half_t* __restrict__ ChhO,
    half_t* __restrict__ ChlO, unsigned char* __restrict__ Ch8O,
    float* __restrict__ Ch32O) {
  __shared__ float cs[512];
  const int node = blockIdx.x, t = threadIdx.x;
  cs[t] = Cin32[(size_t)node * TWO_D + t];
  cs[t + 256] = Cin32[(size_t)node * TWO_D + 256 + t];
  __syncthreads();
  float s = Wb[t];
  #pragma unroll
  for (int sl = 0; sl < 16; ++sl)
    s += part[((size_t)sl * 1024 + node) * DD + t];
  float lin = 0.f;
  #pragma unroll 8
  for (int b = 0; b < 512; ++b) lin += cs[b] * WwT[(size_t)b * DD + t];
  float h = tanhf(s + lin);
  size_t o = (size_t)node * DD + t;
  reps_out[o] = h;
  half_t hh = (half_t)h;
  ChhO[o] = hh;
  ChlO[o] = (half_t)(h - (float)hh);
  Ch8O[o] = to_fp8(h);
  Ch32O[o] = h;
}

// ---- head: logits + softmax + postorder scatter ----------------------------
__global__ __launch_bounds__(64) void k_head(
    const float* __restrict__ reps, const float* __restrict__ Wsw,
    const float* __restrict__ Wsb, float* __restrict__ out) {
  const int nid = blockIdx.x;
  const int lane = threadIdx.x;
  const float4 rv = *(const float4*)(reps + (size_t)nid * DD + lane * 4);
  float lg[5];
  #pragma unroll
  for (int c = 0; c < 5; ++c) {
    const float4 wvv = *(const float4*)(Wsw + c * DD + lane * 4);
    float pth = rv.x * wvv.x + rv.y * wvv.y + rv.z * wvv.z + rv.w * wvv.w;
    pth += __shfl_xor(pth, 1); pth += __shfl_xor(pth, 2); pth += __shfl_xor(pth, 4);
    pth += __shfl_xor(pth, 8); pth += __shfl_xor(pth, 16); pth += __shfl_xor(pth, 32);
    lg[c] = pth + Wsb[c];
  }
  if (lane == 0) {
    const int offs[13] = {0, 2048, 3072, 3584, 3840, 3968, 4032,
                          4064, 4080, 4088, 4092, 4094, 4095};
    int lvl = 0;
    while (nid >= offs[lvl + 1]) lvl++;
    int pp = nid - offs[lvl];
    int idx = (1 << (lvl + 1)) - 2;
    for (int m = lvl; m <= 10; ++m)
      idx += ((pp >> (m - lvl)) & 1) * ((1 << (m + 1)) - 1);
    float mx = lg[0];
    #pragma unroll
    for (int c = 1; c < 5; ++c) mx = fmaxf(mx, lg[c]);
    float e[5], sum = 0.f;
    #pragma unroll
    for (int c = 0; c < 5; ++c) { e[c] = __expf(lg[c] - mx); sum += e[c]; }
    float inv = 1.f / sum;
    #pragma unroll
    for (int c = 0; c < 5; ++c) out[(size_t)idx * 5 + c] = e[c] * inv;
  }
}

extern "C" void kernel_launch(void* const* d_in, const int* in_sizes, int n_in,
                              void* d_out, int out_size, void* d_ws, size_t ws_size,
                              hipStream_t stream) {
  const int* tok = (const int*)d_in[0];
  const float* emb = (const float*)d_in[1];
  const float* V = (const float*)d_in[2];
  const float* Ww = (const float*)d_in[3];
  const float* Wb = (const float*)d_in[4];
  const float* Wsw = (const float*)d_in[5];
  const float* Wsb = (const float*)d_in[6];
  float* out = (float*)d_out;

  // workspace carve (~233 MB)
  char* w = (char*)d_ws;
  half_t* Vth = (half_t*)w;                 w += (size_t)MW_ * TWO_D * 2;   // 134 MB
  unsigned char* Vtl8 = (unsigned char*)w;  w += (size_t)MW_ * TWO_D;       // 67 MB
  float* WwT = (float*)w;                   w += (size_t)TWO_D * DD * 4;    // 0.5 MB
  half_t* ChhA = (half_t*)w;                w += (size_t)2048 * DD * 2;
  half_t* ChhB = (half_t*)w;                w += (size_t)2048 * DD * 2;
  half_t* ChlA = (half_t*)w;                w += (size_t)2048 * DD * 2;
  half_t* ChlB = (half_t*)w;                w += (size_t)2048 * DD * 2;
  unsigned char* Ch8A = (unsigned char*)w;  w += (size_t)2048 * DD;
  unsigned char* Ch8B = (unsigned char*)w;  w += (size_t)2048 * DD;
  float* Ch32A = (float*)w;                 w += (size_t)2048 * DD * 4;
  float* Ch32B = (float*)w;                 w += (size_t)2048 * DD * 4;
  float* reps = (float*)w;                  w += (size_t)4096 * DD * 4;     // 4 MB
  float* part = (float*)w;                  w += (size_t)16 * 1024 * DD * 4; // 16 MB

  hipLaunchKernelGGL(k_split_v, dim3(512, 16), dim3(256), 0, stream, V, Vth, Vtl8);
  hipLaunchKernelGGL(k_prep_w, dim3(512), dim3(256), 0, stream, Ww, WwT);
  hipLaunchKernelGGL(k_leaves, dim3(2048), dim3(256), 0, stream,
                     tok, emb, reps, ChhA, ChlA, Ch8A, Ch32A);

  const int offs[12] = {0, 2048, 3072, 3584, 3840, 3968, 4032, 4064, 4080, 4088, 4092, 4094};
  for (int lvl = 1; lvl <= 11; ++lvl) {
    int n = 2048 >> lvl;
    int bn = (n + 127) / 128;
    bool odd = (lvl & 1) != 0;
    const half_t* Chh_in = odd ? ChhA : ChhB;
    const half_t* Chl_in = odd ? ChlA : ChlB;
    const unsigned char* Ch8_in = odd ? Ch8A : Ch8B;
    const float* Ch32_in = odd ? Ch32A : Ch32B;
    half_t* Chh_out = odd ? ChhB : ChhA;
    half_t* Chl_out = odd ? ChlB : ChlA;
    unsigned char* Ch8_out = odd ? Ch8B : Ch8A;
    float* Ch32_out = odd ? Ch32B : Ch32A;
    hipLaunchKernelGGL(k_level_a, dim3(64 * bn, 8), dim3(512), 98304, stream,
                       Chh_in, Chl_in, Ch8_in, Ch32_in, Vth, Vtl8, part, n);
    hipLaunchKernelGGL(k_level_b, dim3(n), dim3(256), 0, stream,
                       part, WwT, Wb, Ch32_in, reps + (size_t)offs[lvl] * DD,
                       Chh_out, Chl_out, Ch8_out, Ch32_out);
  }
  hipLaunchKernelGGL(k_head, dim3(4095), dim3(64), 0, stream, reps, Wsw, Wsb, out);
}

// Round 4
// 3273.289 us; speedup vs baseline: 1.2666x; 1.2666x over previous
//
#include <hip/hip_runtime.h>
#include <hip/hip_fp16.h>

// RNTensorN: 11-level binary-tree RNTN, L=2048, D=256, C=5.
// Split-precision MFMA scheme (unchanged from round 2, verified absmax 9.8e-4):
//   c = c_hi(f16)+c_lo(f16); V = V_hi(f16) + V_lo8(fp8 e4m3, scale 2^16)
//   G = c_hi@V_hi + c_lo@V_hi (f16 MFMA) + c8@V_lo8 (fp8 MFMA, x 2^-16)
// Round 3/4: node-chunk loop INSIDE k_level_a (V read ~once per level instead
// of n/128 times), 256 blocks (1/CU), AT=8 a's per block, A-frags resident.
// (Round 3 submission never ran: GPU acquisition timeout. Identical resubmit.)

#define DD 256
#define TWO_D 512
#define MW_ 131072      // 2D*D columns of Vm
#define AT 8            // a's per block (phase A)

typedef _Float16 half_t;
typedef _Float16 half8_t __attribute__((ext_vector_type(8)));
typedef float f32x4 __attribute__((ext_vector_type(4)));
typedef long i64t;

#define MFMA16(A, B, C) __builtin_amdgcn_mfma_f32_16x16x32_f16(A, B, C, 0, 0, 0)
#define MFMA8(A, B, C) __builtin_amdgcn_mfma_f32_16x16x32_fp8_fp8(A, B, C, 0, 0, 0)

__device__ __forceinline__ void gll16(const void* g, void* l) {
  __builtin_amdgcn_global_load_lds(
      (const __attribute__((address_space(1))) unsigned int*)g,
      (__attribute__((address_space(3))) unsigned int*)l, 16, 0, 0);
}

__device__ __forceinline__ unsigned char to_fp8(float v) {
  return (unsigned char)(__builtin_amdgcn_cvt_pk_fp8_f32(v, 0.f, 0, false) & 0xff);
}

// ---- V split+transpose: V[k][m] f32 -> Vth[m][k] f16, Vtl8[m][k] fp8*2^16 --
__global__ __launch_bounds__(256) void k_split_v(
    const float* __restrict__ V, half_t* __restrict__ Vth,
    unsigned char* __restrict__ Vtl8) {
  __shared__ unsigned short lh[32][264];
  __shared__ unsigned char ll[32][264];
  const int t = threadIdx.x;
  const int m0 = blockIdx.x * 256;
  const int i0 = blockIdx.y * 32;
  #pragma unroll
  for (int r = 0; r < 32; ++r) {
    float v = V[(size_t)(i0 + r) * MW_ + m0 + t];
    half_t h = (half_t)v;
    lh[r][t] = *(unsigned short*)&h;
    ll[r][t] = to_fp8((v - (float)h) * 65536.f);
  }
  __syncthreads();
  unsigned int wb[16];
  #pragma unroll
  for (int k = 0; k < 16; ++k)
    wb[k] = (unsigned int)lh[2 * k][t] | ((unsigned int)lh[2 * k + 1][t] << 16);
  uint4* dh = (uint4*)(Vth + (size_t)(m0 + t) * TWO_D + i0);
  dh[0] = make_uint4(wb[0], wb[1], wb[2], wb[3]);
  dh[1] = make_uint4(wb[4], wb[5], wb[6], wb[7]);
  dh[2] = make_uint4(wb[8], wb[9], wb[10], wb[11]);
  dh[3] = make_uint4(wb[12], wb[13], wb[14], wb[15]);
  unsigned int b8[8];
  #pragma unroll
  for (int j = 0; j < 8; ++j)
    b8[j] = (unsigned int)ll[4 * j][t] | ((unsigned int)ll[4 * j + 1][t] << 8) |
            ((unsigned int)ll[4 * j + 2][t] << 16) |
            ((unsigned int)ll[4 * j + 3][t] << 24);
  uint4* dl = (uint4*)(Vtl8 + (size_t)(m0 + t) * TWO_D + i0);
  dl[0] = make_uint4(b8[0], b8[1], b8[2], b8[3]);
  dl[1] = make_uint4(b8[4], b8[5], b8[6], b8[7]);
}

// ---- WwT[b][a] = Ww[a][b] (f32), for the phase-B linear term ---------------
__global__ void k_prep_w(const float* __restrict__ Ww, float* __restrict__ WwT) {
  const int b = blockIdx.x, t = threadIdx.x;
  WwT[(size_t)b * DD + t] = Ww[(size_t)t * TWO_D + b];
}

// ---- leaves: gather embeddings -> reps f32 + all c-representations ---------
__global__ void k_leaves(const int* __restrict__ tok, const float* __restrict__ emb,
                         float* __restrict__ reps, half_t* __restrict__ Chh,
                         half_t* __restrict__ Chl, unsigned char* __restrict__ Ch8,
                         float* __restrict__ Ch32) {
  const int row = blockIdx.x, t = threadIdx.x;
  float v = emb[(size_t)tok[row] * DD + t];
  size_t o = (size_t)row * DD + t;
  reps[o] = v;
  half_t h = (half_t)v;
  Chh[o] = h;
  Chl[o] = (half_t)(v - (float)h);
  Ch8[o] = to_fp8(v);
  Ch32[o] = v;
}

// ---- phase A: split-precision fused bilinear GEMM --------------------------
// grid (32, 8) = 256 blocks (1/CU). Block = AT=8 a's x 64 b-rows; node-chunks
// of 128 loop inside. 8 waves: kh = wv>>2 (k-half), wq = wv&3 (node quad).
__global__ __launch_bounds__(512, 2) void k_level_a(
    const half_t* __restrict__ Chh, const half_t* __restrict__ Chl,
    const unsigned char* __restrict__ Ch8, const float* __restrict__ Ch32,
    const half_t* __restrict__ Vth, const unsigned char* __restrict__ Vtl8,
    float* __restrict__ part, int n) {
  extern __shared__ char smem[];
  char* R0 = smem;            // 64 KB: V_hi tile, 64 rows x 1024 B
  char* R1 = smem + 65536;    // 32 KB: V_lo8 tile, 64 rows x 512 B
  const int tid = threadIdx.x;
  const int lane = tid & 63;
  const int wv = tid >> 6;
  const int l15 = lane & 15;
  const int l4 = lane >> 4;
  const int kh = wv >> 2;
  const int wq = wv & 3;
  const int bz = blockIdx.y;
  const int a_base = blockIdx.x * AT;
  const int swz = (l15 & 7) << 4;
  const int kbase = kh * 256;       // this wave's k-half (elements)
  const int nch = (n + 127) >> 7;

  half8_t afh0[8], afh1[8], afl0[8], afl1[8];
  i64t af80[8], af81[8];

  auto stage_vhi = [&](int a) {
    const size_t mb = ((size_t)(a_base + a) * TWO_D + bz * 64) * 1024;
    #pragma unroll
    for (int j = 0; j < 8; ++j) {
      int row = wv * 8 + j;
      int so = (lane * 16) ^ ((row & 7) << 4);
      gll16((const char*)Vth + mb + (size_t)row * 1024 + so, R0 + row * 1024);
    }
  };
  auto stage_vlo = [&](int a) {
    const size_t mb = ((size_t)(a_base + a) * TWO_D + bz * 64) * 512;
    #pragma unroll
    for (int j = 0; j < 4; ++j) {
      int r0 = wv * 8 + j * 2;
      int row = r0 + (lane >> 5);
      int so = ((lane & 31) * 16) ^ ((row & 7) << 4);
      gll16((const char*)Vtl8 + mb + (size_t)row * 512 + so, R1 + r0 * 512);
    }
  };

  stage_vhi(0);   // first tile of chunk 0

  #pragma unroll 1
  for (int ch = 0; ch < nch; ++ch) {
    const int nbase0 = ch * 128 + wq * 32;
    const int nbase1 = nbase0 + 16;
    const bool act = (nbase0 < n);    // wave-uniform

    if (act) {  // A fragments for this chunk, resident across all AT a's
      int node0 = nbase0 + l15, node1 = nbase1 + l15;
      bool ok0 = node0 < n, ok1 = node1 < n;
      const half8_t z = {};
      const size_t o0 = (size_t)node0 * TWO_D + kbase + 8 * l4;
      const size_t o1 = (size_t)node1 * TWO_D + kbase + 8 * l4;
      #pragma unroll
      for (int kc = 0; kc < 8; ++kc) {
        half8_t a0 = *(const half8_t*)(Chh + o0 + kc * 32);
        half8_t a1 = *(const half8_t*)(Chh + o1 + kc * 32);
        half8_t b0 = *(const half8_t*)(Chl + o0 + kc * 32);
        half8_t b1 = *(const half8_t*)(Chl + o1 + kc * 32);
        i64t c0 = *(const i64t*)(Ch8 + o0 + kc * 32);
        i64t c1 = *(const i64t*)(Ch8 + o1 + kc * 32);
        afh0[kc] = ok0 ? a0 : z;   afh1[kc] = ok1 ? a1 : z;
        afl0[kc] = ok0 ? b0 : z;   afl1[kc] = ok1 ? b1 : z;
        af80[kc] = ok0 ? c0 : (i64t)0; af81[kc] = ok1 ? c1 : (i64t)0;
      }
    }

    #pragma unroll 1
    for (int a = 0; a < AT; ++a) {
      const f32x4 zz = {0.f, 0.f, 0.f, 0.f};
      f32x4 accA[4] = {zz, zz, zz, zz};
      f32x4 accB[4] = {zz, zz, zz, zz};

      __syncthreads();                  // R0 = V_hi(a) landed; R1 free
      stage_vlo(a);                     // -> R1 (overlaps HI pass)

      if (act) {  // HI pass: G1 (c_hi@V_hi) + G2 (c_lo@V_hi)
        const int xb = kbase * 2;
        #pragma unroll
        for (int kc = 0; kc < 8; ++kc) {
          int xo = (xb + kc * 64 + 16 * l4) ^ swz;
          const char* bp = R0 + l15 * 1024 + xo;
          half8_t b0 = *(const half8_t*)(bp);
          half8_t b1 = *(const half8_t*)(bp + 16384);
          half8_t b2 = *(const half8_t*)(bp + 32768);
          half8_t b3 = *(const half8_t*)(bp + 49152);
          accA[0] = MFMA16(afh0[kc], b0, accA[0]);
          accA[0] = MFMA16(afl0[kc], b0, accA[0]);
          accB[0] = MFMA16(afh1[kc], b0, accB[0]);
          accB[0] = MFMA16(afl1[kc], b0, accB[0]);
          accA[1] = MFMA16(afh0[kc], b1, accA[1]);
          accA[1] = MFMA16(afl0[kc], b1, accA[1]);
          accB[1] = MFMA16(afh1[kc], b1, accB[1]);
          accB[1] = MFMA16(afl1[kc], b1, accB[1]);
          accA[2] = MFMA16(afh0[kc], b2, accA[2]);
          accA[2] = MFMA16(afl0[kc], b2, accA[2]);
          accB[2] = MFMA16(afh1[kc], b2, accB[2]);
          accB[2] = MFMA16(afl1[kc], b2, accB[2]);
          accA[3] = MFMA16(afh0[kc], b3, accA[3]);
          accA[3] = MFMA16(afl0[kc], b3, accA[3]);
          accB[3] = MFMA16(afh1[kc], b3, accB[3]);
          accB[3] = MFMA16(afl1[kc], b3, accB[3]);
        }
      }

      __syncthreads();                  // R1 landed; R0 free
      if (a + 1 < AT) stage_vhi(a + 1); // -> R0 (overlaps LO pass)
      else if (ch + 1 < nch) stage_vhi(0);

      if (act) {
        // LO pass: G3 = c8 @ V_lo8, descale 2^-16 into f32 acc
        #pragma unroll
        for (int mt = 0; mt < 4; ++mt) {
          f32x4 p0 = zz, p1 = zz;
          #pragma unroll
          for (int kc = 0; kc < 8; ++kc) {
            int xo = (kbase + kc * 32 + 8 * l4) ^ swz;
            i64t bb = *(const i64t*)(R1 + (mt * 16 + l15) * 512 + xo);
            p0 = MFMA8(af80[kc], bb, p0);
            p1 = MFMA8(af81[kc], bb, p1);
          }
          accA[mt] += p0 * 1.52587890625e-05f;
          accB[mt] += p1 * 1.52587890625e-05f;
        }

        // stage 2: tens partial = sum_b G[n][b] * c32[n][b]
        float aS0[4] = {0.f, 0.f, 0.f, 0.f};
        float aS1[4] = {0.f, 0.f, 0.f, 0.f};
        {
          int bc = bz * 64 + l15;
          #pragma unroll
          for (int mt = 0; mt < 4; ++mt) {
            #pragma unroll
            for (int r = 0; r < 4; ++r) {
              int rr = 4 * l4 + r;
              float w0 = Ch32[(size_t)(nbase0 + rr) * TWO_D + bc + mt * 16];
              float w1 = Ch32[(size_t)(nbase1 + rr) * TWO_D + bc + mt * 16];
              aS0[r] += w0 * accA[mt][r];
              aS1[r] += w1 * accB[mt][r];
            }
          }
        }
        #pragma unroll
        for (int r = 0; r < 4; ++r) {
          float v0 = aS0[r], v1 = aS1[r];
          v0 += __shfl_xor(v0, 1); v0 += __shfl_xor(v0, 2);
          v0 += __shfl_xor(v0, 4); v0 += __shfl_xor(v0, 8);
          v1 += __shfl_xor(v1, 1); v1 += __shfl_xor(v1, 2);
          v1 += __shfl_xor(v1, 4); v1 += __shfl_xor(v1, 8);
          aS0[r] = v0; aS1[r] = v1;
        }
        if (l15 < 4) {
          int a_glob = a_base + a;
          float o0 = (l15 == 0) ? aS0[0] : (l15 == 1) ? aS0[1] : (l15 == 2) ? aS0[2] : aS0[3];
          float o1 = (l15 == 0) ? aS1[0] : (l15 == 1) ? aS1[1] : (l15 == 2) ? aS1[2] : aS1[3];
          int n0 = nbase0 + 4 * l4 + l15;
          int n1 = nbase1 + 4 * l4 + l15;
          size_t sl = (size_t)(bz * 2 + kh) * 1024;
          if (n0 < n) part[(sl + n0) * DD + a_glob] = o0;
          if (n1 < n) part[(sl + n1) * DD + a_glob] = o1;
        }
      }
    }
  }
}

// ---- phase B: sum 16 partial slices + f32 linear term + bias + tanh --------
__global__ __launch_bounds__(256) void k_level_b(
    const float* __restrict__ part, const float* __restrict__ WwT,
    const float* __restrict__ Wb, const float* __restrict__ Cin32,
    float* __restrict__ reps_out, half_t* __restrict__ ChhO,
    half_t* __restrict__ ChlO, unsigned char* __restrict__ Ch8O,
    float* __restrict__ Ch32O) {
  __shared__ float cs[512];
  const int node = blockIdx.x, t = threadIdx.x;
  cs[t] = Cin32[(size_t)node * TWO_D + t];
  cs[t + 256] = Cin32[(size_t)node * TWO_D + 256 + t];
  __syncthreads();
  float s = Wb[t];
  #pragma unroll
  for (int sl = 0; sl < 16; ++sl)
    s += part[((size_t)sl * 1024 + node) * DD + t];
  float lin = 0.f;
  #pragma unroll 8
  for (int b = 0; b < 512; ++b) lin += cs[b] * WwT[(size_t)b * DD + t];
  float h = tanhf(s + lin);
  size_t o = (size_t)node * DD + t;
  reps_out[o] = h;
  half_t hh = (half_t)h;
  ChhO[o] = hh;
  ChlO[o] = (half_t)(h - (float)hh);
  Ch8O[o] = to_fp8(h);
  Ch32O[o] = h;
}

// ---- head: logits + softmax + postorder scatter ----------------------------
__global__ __launch_bounds__(64) void k_head(
    const float* __restrict__ reps, const float* __restrict__ Wsw,
    const float* __restrict__ Wsb, float* __restrict__ out) {
  const int nid = blockIdx.x;
  const int lane = threadIdx.x;
  const float4 rv = *(const float4*)(reps + (size_t)nid * DD + lane * 4);
  float lg[5];
  #pragma unroll
  for (int c = 0; c < 5; ++c) {
    const float4 wvv = *(const float4*)(Wsw + c * DD + lane * 4);
    float pth = rv.x * wvv.x + rv.y * wvv.y + rv.z * wvv.z + rv.w * wvv.w;
    pth += __shfl_xor(pth, 1); pth += __shfl_xor(pth, 2); pth += __shfl_xor(pth, 4);
    pth += __shfl_xor(pth, 8); pth += __shfl_xor(pth, 16); pth += __shfl_xor(pth, 32);
    lg[c] = pth + Wsb[c];
  }
  if (lane == 0) {
    const int offs[13] = {0, 2048, 3072, 3584, 3840, 3968, 4032,
                          4064, 4080, 4088, 4092, 4094, 4095};
    int lvl = 0;
    while (nid >= offs[lvl + 1]) lvl++;
    int pp = nid - offs[lvl];
    int idx = (1 << (lvl + 1)) - 2;
    for (int m = lvl; m <= 10; ++m)
      idx += ((pp >> (m - lvl)) & 1) * ((1 << (m + 1)) - 1);
    float mx = lg[0];
    #pragma unroll
    for (int c = 1; c < 5; ++c) mx = fmaxf(mx, lg[c]);
    float e[5], sum = 0.f;
    #pragma unroll
    for (int c = 0; c < 5; ++c) { e[c] = __expf(lg[c] - mx); sum += e[c]; }
    float inv = 1.f / sum;
    #pragma unroll
    for (int c = 0; c < 5; ++c) out[(size_t)idx * 5 + c] = e[c] * inv;
  }
}

extern "C" void kernel_launch(void* const* d_in, const int* in_sizes, int n_in,
                              void* d_out, int out_size, void* d_ws, size_t ws_size,
                              hipStream_t stream) {
  const int* tok = (const int*)d_in[0];
  const float* emb = (const float*)d_in[1];
  const float* V = (const float*)d_in[2];
  const float* Ww = (const float*)d_in[3];
  const float* Wb = (const float*)d_in[4];
  const float* Wsw = (const float*)d_in[5];
  const float* Wsb = (const float*)d_in[6];
  float* out = (float*)d_out;

  // workspace carve (~233 MB)
  char* w = (char*)d_ws;
  half_t* Vth = (half_t*)w;                 w += (size_t)MW_ * TWO_D * 2;   // 134 MB
  unsigned char* Vtl8 = (unsigned char*)w;  w += (size_t)MW_ * TWO_D;       // 67 MB
  float* WwT = (float*)w;                   w += (size_t)TWO_D * DD * 4;    // 0.5 MB
  half_t* ChhA = (half_t*)w;                w += (size_t)2048 * DD * 2;
  half_t* ChhB = (half_t*)w;                w += (size_t)2048 * DD * 2;
  half_t* ChlA = (half_t*)w;                w += (size_t)2048 * DD * 2;
  half_t* ChlB = (half_t*)w;                w += (size_t)2048 * DD * 2;
  unsigned char* Ch8A = (unsigned char*)w;  w += (size_t)2048 * DD;
  unsigned char* Ch8B = (unsigned char*)w;  w += (size_t)2048 * DD;
  float* Ch32A = (float*)w;                 w += (size_t)2048 * DD * 4;
  float* Ch32B = (float*)w;                 w += (size_t)2048 * DD * 4;
  float* reps = (float*)w;                  w += (size_t)4096 * DD * 4;     // 4 MB
  float* part = (float*)w;                  w += (size_t)16 * 1024 * DD * 4; // 16 MB

  hipLaunchKernelGGL(k_split_v, dim3(512, 16), dim3(256), 0, stream, V, Vth, Vtl8);
  hipLaunchKernelGGL(k_prep_w, dim3(512), dim3(256), 0, stream, Ww, WwT);
  hipLaunchKernelGGL(k_leaves, dim3(2048), dim3(256), 0, stream,
                     tok, emb, reps, ChhA, ChlA, Ch8A, Ch32A);

  const int offs[12] = {0, 2048, 3072, 3584, 3840, 3968, 4032, 4064, 4080, 4088, 4092, 4094};
  for (int lvl = 1; lvl <= 11; ++lvl) {
    int n = 2048 >> lvl;
    bool odd = (lvl & 1) != 0;
    const half_t* Chh_in = odd ? ChhA : ChhB;
    const half_t* Chl_in = odd ? ChlA : ChlB;
    const unsigned char* Ch8_in = odd ? Ch8A : Ch8B;
    const float* Ch32_in = odd ? Ch32A : Ch32B;
    half_t* Chh_out = odd ? ChhB : ChhA;
    half_t* Chl_out = odd ? ChlB : ChlA;
    unsigned char* Ch8_out = odd ? Ch8B : Ch8A;
    float* Ch32_out = odd ? Ch32B : Ch32A;
    hipLaunchKernelGGL(k_level_a, dim3(32, 8), dim3(512), 98304, stream,
                       Chh_in, Chl_in, Ch8_in, Ch32_in, Vth, Vtl8, part, n);
    hipLaunchKernelGGL(k_level_b, dim3(n), dim3(256), 0, stream,
                       part, WwT, Wb, Ch32_in, reps + (size_t)offs[lvl] * DD,
                       Chh_out, Chl_out, Ch8_out, Ch32_out);
  }
  hipLaunchKernelGGL(k_head, dim3(4095), dim3(64), 0, stream, reps, Wsw, Wsb, out);
}